// Round 4
// baseline (200.758 us; speedup 1.0000x reference)
//
#include <hip/hip_runtime.h>

#define B_ 4
#define L_ 4096
#define D_ 1024
#define N_ 64

typedef _Float16 f16;
typedef __attribute__((ext_vector_type(8))) _Float16 half8;
typedef __attribute__((ext_vector_type(4))) float f32x4;

__device__ __forceinline__ float softplus_f(float x) {
    return fmaxf(x, 0.0f) + log1pf(__expf(-fabsf(x)));
}

__device__ __forceinline__ float tanh_f(float x) {
    float xc = fminf(fmaxf(x, -15.0f), 15.0f);
    float e = __expf(2.0f * xc);
    return (e - 1.0f) / (e + 1.0f);
}

// ---------------------------------------------------------------------------
// Prep: WT [192][1024] fp16 (rows 0-127 = Wp cols, 128-191 = Ws cols);
// WoT [1024][64] fp16 (WoT[d][n] = Wo[n][d]).
// ---------------------------------------------------------------------------
__global__ __launch_bounds__(256) void k_prepw(
    const float* __restrict__ Wp, const float* __restrict__ Ws,
    const float* __restrict__ Wo, f16* __restrict__ WT, f16* __restrict__ WoT)
{
    int gid = blockIdx.x * 256 + threadIdx.x;
    if (gid < 24576) {
        int r = gid >> 7, kg = gid & 127;
        const float* src; int ncol, c;
        if (r < 128) { src = Wp; ncol = 128; c = r; }
        else         { src = Ws; ncol = 64;  c = r - 128; }
        f16 h[8];
        #pragma unroll
        for (int j = 0; j < 8; j++)
            h[j] = (f16)src[(size_t)(kg * 8 + j) * ncol + c];
        *(uint4*)&WT[(size_t)r * 1024 + kg * 8] = *(uint4*)h;
    } else {
        int g2 = gid - 24576;                 // < 8192
        int d = g2 >> 3, ng = g2 & 7;
        f16 h[8];
        #pragma unroll
        for (int j = 0; j < 8; j++)
            h[j] = (f16)Wo[(size_t)(ng * 8 + j) * D_ + d];
        *(uint4*)&WoT[(size_t)d * 64 + ng * 8] = *(uint4*)h;
    }
}

// ---------------------------------------------------------------------------
// Fused frontend v5: 256 thr / 4 waves, 16 tokens/block, 1024 blocks.
// BARRIER-FREE K-loop: whole x tile (20 rows x 1024 d, f16, 41.6KB) staged
// ONCE; conv chunk (16 x 1024, 33.3KB) computed ONCE; then 32 ks-steps of
// pure {WT L2 loads + LDS b-frags + MFMA} with no __syncthreads -> no
// per-chunk vmcnt(0) drains, free compiler pipelining.  4 barriers total.
// LDS row stride 1040 f16 (520 dw = 8 mod 32 -> 2-way conflicts = free).
// ---------------------------------------------------------------------------
#define XS 1040   // f16 row stride
__global__ __launch_bounds__(256) void k_frontend(
    const float* __restrict__ x, const float* __restrict__ conv_w,
    const float* __restrict__ conv_b, const f16* __restrict__ WT,
    const float* __restrict__ bp, const float* __restrict__ bs,
    const float* __restrict__ dt_log,
    f16* __restrict__ zT, f16* __restrict__ cT)
{
    // xh [20][XS] f16 @0 (41600B); ch [16][XS] f16 @41600 (33280B) = 74880B
    // sE [3][16][68] f32 (13056B) aliases @0 after the K-loop.
    __shared__ __align__(16) char smem[74880];
    f16*   xh = (f16*)smem;
    f16*   ch = (f16*)(smem + 41600);
    float* sE = (float*)smem;

    const int tid = threadIdx.x;
    const int w = tid >> 6, lane = tid & 63;
    const int r = lane & 15, q = lane >> 4;
    const int T0 = blockIdx.x * 16;
    const int bb = T0 >> 12;
    const int l0 = T0 & (L_ - 1);
    const int cw0 = w * 48;

    // --- phase 1: stage whole x tile -> xh (f16). 5120 float4 slots. ---
    #pragma unroll
    for (int s = 0; s < 20; s++) {
        int idx = tid + 256 * s;
        int row = idx >> 8, g = idx & 255;
        int l = l0 + row - 4;
        float4 v = make_float4(0.f, 0.f, 0.f, 0.f);
        if (l >= 0)
            v = *(const float4*)&x[((size_t)(bb * L_ + l)) * D_ + g * 4];
        f16 h[4] = {(f16)v.x, (f16)v.y, (f16)v.z, (f16)v.w};
        *(uint2*)&xh[row * XS + g * 4] = *(uint2*)h;
    }
    __syncthreads();

    // --- phase 2: conv -> ch, once.  Thread owns dims [tid*4, tid*4+4),
    //     all 16 tokens, rolling 4-row window over xh rows 1..19. ---
    {
        const int d0 = tid * 4;
        const float4 w0 = *(const float4*)&conv_w[0 * D_ + d0];
        const float4 w1 = *(const float4*)&conv_w[1 * D_ + d0];
        const float4 w2 = *(const float4*)&conv_w[2 * D_ + d0];
        const float4 w3 = *(const float4*)&conv_w[3 * D_ + d0];
        const float4 cb = *(const float4*)&conv_b[d0];
        const float cwv[4][4] = {{w0.x,w0.y,w0.z,w0.w},{w1.x,w1.y,w1.z,w1.w},
                                 {w2.x,w2.y,w2.z,w2.w},{w3.x,w3.y,w3.z,w3.w}};
        const float cbv[4] = {cb.x, cb.y, cb.z, cb.w};
        uint2 win[4];
        win[0] = *(const uint2*)&xh[1 * XS + d0];
        win[1] = *(const uint2*)&xh[2 * XS + d0];
        win[2] = *(const uint2*)&xh[3 * XS + d0];
        #pragma unroll
        for (int t = 0; t < 16; t++) {
            win[3] = *(const uint2*)&xh[(t + 4) * XS + d0];
            const f16* x0 = (const f16*)&win[0];
            const f16* x1 = (const f16*)&win[1];
            const f16* x2 = (const f16*)&win[2];
            const f16* x3 = (const f16*)&win[3];
            f16 ho[4];
            #pragma unroll
            for (int j = 0; j < 4; j++) {
                float s = cbv[j];
                s = fmaf(cwv[0][j], (float)x0[j], s);
                s = fmaf(cwv[1][j], (float)x1[j], s);
                s = fmaf(cwv[2][j], (float)x2[j], s);
                s = fmaf(cwv[3][j], (float)x3[j], s);
                ho[j] = (f16)s;
            }
            *(uint2*)&ch[t * XS + d0] = *(uint2*)ho;
            win[0] = win[1]; win[1] = win[2]; win[2] = win[3];
        }
    }
    __syncthreads();

    // --- phase 3: barrier-free K-loop (32 steps of K=32) ---
    f32x4 acc[3] = {};
    const bool needC = (cw0 < 128);          // w 0,1,2
    const bool needR = (cw0 + 32 >= 128);    // w 2,3
    const bool uc0 = (cw0      < 128);
    const bool uc1 = (cw0 + 16 < 128);
    const bool uc2 = (cw0 + 32 < 128);
    const int klq = q * 8;
    #pragma unroll 4
    for (int j = 0; j < 32; j++) {
        const int kk = j * 32 + klq;
        half8 a0 = *(const half8*)&WT[(size_t)(cw0 +      r) * 1024 + kk];
        half8 a1 = *(const half8*)&WT[(size_t)(cw0 + 16 + r) * 1024 + kk];
        half8 a2 = *(const half8*)&WT[(size_t)(cw0 + 32 + r) * 1024 + kk];
        half8 bc = {}, br = {};
        if (needC) bc = *(const half8*)&ch[r * XS + kk];
        if (needR) br = *(const half8*)&xh[(r + 4) * XS + kk];
        acc[0] = __builtin_amdgcn_mfma_f32_16x16x32_f16(a0, uc0 ? bc : br, acc[0], 0, 0, 0);
        acc[1] = __builtin_amdgcn_mfma_f32_16x16x32_f16(a1, uc1 ? bc : br, acc[1], 0, 0, 0);
        acc[2] = __builtin_amdgcn_mfma_f32_16x16x32_f16(a2, uc2 ? bc : br, acc[2], 0, 0, 0);
    }

    // --- epilogue: bias + activation -> sE (aliases xh/ch) ---
    float* sB = sE;
    float* sC = sE + 16 * 68;
    float* sU = sE + 2 * 16 * 68;
    __syncthreads();   // all LDS reads done before alias overwrite
    #pragma unroll
    for (int mf = 0; mf < 3; mf++) {
        const int cb4 = cw0 + mf * 16 + q * 4;
        const int seg = cb4 >> 6;          // 0=Bt 1=Ct 2=u (frag-uniform)
        const int cl = cb4 & 63;
        const float4 bb4 = (seg == 2) ? *(const float4*)&bs[cl]
                                      : *(const float4*)&bp[cb4];
        float* dst = (seg == 0) ? sB : (seg == 1 ? sC : sU);
        float v0 = acc[mf][0] + bb4.x;
        float v1 = acc[mf][1] + bb4.y;
        float v2 = acc[mf][2] + bb4.z;
        float v3 = acc[mf][3] + bb4.w;
        if (seg == 0) {
            v0 = softplus_f(v0); v1 = softplus_f(v1);
            v2 = softplus_f(v2); v3 = softplus_f(v3);
        } else if (seg == 1) {
            v0 = tanh_f(v0); v1 = tanh_f(v1);
            v2 = tanh_f(v2); v3 = tanh_f(v3);
        }
        float4 vv = {v0, v1, v2, v3};
        *(float4*)&dst[r * 68 + cl] = vv;
    }
    __syncthreads();

    // --- fused combine: z = dt[n]*Bt*u, store zT/cT n-major ---
    {
        const int n = tid >> 2, tg = tid & 3;
        const float dtv = softplus_f(dt_log[n]);
        f16 hz[4], hc[4];
        #pragma unroll
        for (int j = 0; j < 4; j++) {
            const int t = tg * 4 + j;
            hz[j] = (f16)(dtv * sB[t * 68 + n] * sU[t * 68 + n]);
            hc[j] = (f16)sC[t * 68 + n];
        }
        size_t o = ((size_t)(bb * N_ + n)) * L_ + l0 + tg * 4;
        *(uint2*)&zT[o] = *(uint2*)hz;
        *(uint2*)&cT[o] = *(uint2*)hc;
    }
}
#undef XS

// ---------------------------------------------------------------------------
// Scan v2: 256 threads per (b,n) chain.  Thread t owns elems [16t,16t+16);
// serial 16-fma local reduce -> 64-lane shfl affine scan -> cross-wave
// stitch via LDS -> apply.  +i>>4 swizzle avoids 32-way bank conflicts.
// ---------------------------------------------------------------------------
#define ZI(i) ((i) + ((i) >> 4))
__global__ __launch_bounds__(256) void k_scan(
    const f16* __restrict__ zT, const f16* __restrict__ cT,
    const float* __restrict__ A_log, const float* __restrict__ dt_log,
    f16* __restrict__ yH)
{
    __shared__ float zs[4352];
    __shared__ float cs[4352];
    __shared__ float sA[4], sB[4];
    const int bn = blockIdx.x;
    const int n = bn & (N_ - 1);
    const int tid = threadIdx.x;
    const int lane = tid & 63, w = tid >> 6;
    const f16* zp = zT + (size_t)bn * L_;
    const f16* cp = cT + (size_t)bn * L_;

    #pragma unroll
    for (int it = 0; it < 2; it++) {
        int i = tid * 8 + it * 2048;
        uint4 rz = *(const uint4*)(zp + i);
        uint4 rc = *(const uint4*)(cp + i);
        const f16* hz = (const f16*)&rz;
        const f16* hc = (const f16*)&rc;
        #pragma unroll
        for (int k = 0; k < 8; k++) {
            zs[ZI(i + k)] = (float)hz[k];
            cs[ZI(i + k)] = (float)hc[k];
        }
    }
    __syncthreads();

    float dtv = softplus_f(dt_log[n]);
    float Av = -softplus_f(A_log[n]);
    float dec = fmaf(dtv, Av, 1.0f);

    const int base = tid * 17;           // ZI(tid*16)
    float s = 0.0f;
    #pragma unroll
    for (int j = 0; j < 16; j++) s = fmaf(dec, s, zs[base + j]);

    float d2 = dec * dec, d4 = d2 * d2, d8 = d4 * d4, d16 = d8 * d8;

    float Ag = d16, Bg = s;
    #pragma unroll
    for (int off = 1; off < 64; off <<= 1) {
        float Ap = __shfl_up(Ag, off);
        float Bp = __shfl_up(Bg, off);
        if (lane >= off) { Bg = fmaf(Ag, Bp, Bg); Ag *= Ap; }
    }
    if (lane == 63) { sA[w] = Ag; sB[w] = Bg; }
    __syncthreads();

    float Bc = 0.0f;                      // carry entering this wave
    for (int i = 0; i < w; i++) Bc = fmaf(sA[i], Bc, sB[i]);
    float Ae = __shfl_up(Ag, 1);          // exclusive within wave
    float Be = __shfl_up(Bg, 1);
    if (lane == 0) { Ae = 1.0f; Be = 0.0f; }
    float carry = fmaf(Ae, Bc, Be);       // state entering this thread

    float st = carry;
    #pragma unroll
    for (int j = 0; j < 16; j++) {
        st = fmaf(dec, st, zs[base + j]);
        zs[base + j] = cs[base + j] * st;
    }
    __syncthreads();

    f16* yp = yH + (size_t)bn * L_;
    #pragma unroll
    for (int it = 0; it < 2; it++) {
        int i = tid * 8 + it * 2048;
        f16 h[8];
        #pragma unroll
        for (int k = 0; k < 8; k++) h[k] = (f16)zs[ZI(i + k)];
        *(uint4*)&yp[i] = *(uint4*)h;
    }
}
#undef ZI

// ---------------------------------------------------------------------------
// Out GEMM: out[t][d] = y[t][:] @ Wo[:,d] + bo.  A = WoT (m=d), B = y (n=tok)
// -> D rows are d -> float4 coalesced stores.  Block 256 thr: 64 tok x 128 d,
// wave = 32 d x 64 tok.  Grid (256, 8) = 2048 blocks = 8/CU.
// ---------------------------------------------------------------------------
__global__ __launch_bounds__(256) void k_out(
    const f16* __restrict__ yH, const f16* __restrict__ WoT,
    const float* __restrict__ bo, float* __restrict__ out)
{
    __shared__ __align__(16) f16 ys[64 * 72];
    const int tid = threadIdx.x;
    const int w = tid >> 6, lane = tid & 63;
    const int r = lane & 15, q = lane >> 4;
    const int T0 = blockIdx.x * 64;
    const int bb = T0 >> 12, l0 = T0 & (L_ - 1);
    const int dw = blockIdx.y * 128 + w * 32;

    // stage y transpose: [n-major global] -> ys[t][n]
    {
        const int n = tid & 63, tg = tid >> 6;
        #pragma unroll
        for (int h2 = 0; h2 < 2; h2++) {
            uint4 v = *(const uint4*)&yH[((size_t)(bb * N_ + n)) * L_ + l0 + tg * 16 + h2 * 8];
            const f16* hh = (const f16*)&v;
            #pragma unroll
            for (int j = 0; j < 8; j++)
                ys[(tg * 16 + h2 * 8 + j) * 72 + n] = hh[j];
        }
    }
    __syncthreads();

    f32x4 acc[2][4] = {};
    #pragma unroll
    for (int ks = 0; ks < 2; ks++) {
        const int kk = ks * 32 + q * 8;
        half8 af[2];
        #pragma unroll
        for (int mf = 0; mf < 2; mf++)
            af[mf] = *(const half8*)&WoT[(size_t)(dw + mf * 16 + r) * 64 + kk];
        #pragma unroll
        for (int nf = 0; nf < 4; nf++) {
            half8 bf = *(const half8*)&ys[(nf * 16 + r) * 72 + kk];
            #pragma unroll
            for (int mf = 0; mf < 2; mf++)
                acc[mf][nf] = __builtin_amdgcn_mfma_f32_16x16x32_f16(
                    af[mf], bf, acc[mf][nf], 0, 0, 0);
        }
    }

    #pragma unroll
    for (int mf = 0; mf < 2; mf++) {
        const int d = dw + mf * 16 + q * 4;
        const float4 bb4 = *(const float4*)&bo[d];
        #pragma unroll
        for (int nf = 0; nf < 4; nf++) {
            const int t = T0 + nf * 16 + r;
            float4 o = {acc[mf][nf][0] + bb4.x, acc[mf][nf][1] + bb4.y,
                        acc[mf][nf][2] + bb4.z, acc[mf][nf][3] + bb4.w};
            *(float4*)&out[(size_t)t * D_ + d] = o;
        }
    }
}

// ---------------------------------------------------------------------------
extern "C" void kernel_launch(void* const* d_in, const int* in_sizes, int n_in,
                              void* d_out, int out_size, void* d_ws, size_t ws_size,
                              hipStream_t stream) {
    const float* x      = (const float*)d_in[0];
    const float* conv_w = (const float*)d_in[1];
    const float* conv_b = (const float*)d_in[2];
    const float* Wp     = (const float*)d_in[3];
    const float* bp     = (const float*)d_in[4];
    const float* Ws     = (const float*)d_in[5];
    const float* bs     = (const float*)d_in[6];
    const float* A_log  = (const float*)d_in[7];
    const float* dt_log = (const float*)d_in[8];
    const float* Wo     = (const float*)d_in[9];
    const float* bo     = (const float*)d_in[10];
    float* out = (float*)d_out;

    char* wsp = (char*)d_ws;
    f16* WT  = (f16*)wsp;                     // 384 KB
    f16* WoT = (f16*)(wsp + 393216);          // 128 KB
    f16* zT  = (f16*)(wsp + 524288);          // 2 MB [B,N,L]
    f16* cT  = (f16*)(wsp + 2621440);         // 2 MB
    f16* yH  = (f16*)(wsp + 4718592);         // 2 MB

    k_prepw<<<dim3(128), dim3(256), 0, stream>>>(Wp, Ws, Wo, WT, WoT);
    k_frontend<<<dim3(B_ * L_ / 16), dim3(256), 0, stream>>>(
        x, conv_w, conv_b, WT, bp, bs, dt_log, zT, cT);
    k_scan<<<dim3(B_ * N_), dim3(256), 0, stream>>>(zT, cT, A_log, dt_log, yH);
    k_out<<<dim3(B_ * L_ / 64, D_ / 128), dim3(256), 0, stream>>>(yH, WoT, bo, out);
}

// Round 5
// 191.224 us; speedup vs baseline: 1.0499x; 1.0499x over previous
//
#include <hip/hip_runtime.h>

#define B_ 4
#define L_ 4096
#define D_ 1024
#define N_ 64

typedef _Float16 f16;
typedef __attribute__((ext_vector_type(8))) _Float16 half8;
typedef __attribute__((ext_vector_type(4))) float f32x4;

__device__ __forceinline__ float softplus_f(float x) {
    return fmaxf(x, 0.0f) + log1pf(__expf(-fabsf(x)));
}

__device__ __forceinline__ float tanh_f(float x) {
    float xc = fminf(fmaxf(x, -15.0f), 15.0f);
    float e = __expf(2.0f * xc);
    return (e - 1.0f) / (e + 1.0f);
}

// ---------------------------------------------------------------------------
// Prep: WT [192][1024] fp16 (rows 0-127 = Wp cols, 128-191 = Ws cols);
// WoT [1024][64] fp16 (WoT[d][n] = Wo[n][d]).
// ---------------------------------------------------------------------------
__global__ __launch_bounds__(256) void k_prepw(
    const float* __restrict__ Wp, const float* __restrict__ Ws,
    const float* __restrict__ Wo, f16* __restrict__ WT, f16* __restrict__ WoT)
{
    int gid = blockIdx.x * 256 + threadIdx.x;
    if (gid < 24576) {
        int r = gid >> 7, kg = gid & 127;
        const float* src; int ncol, c;
        if (r < 128) { src = Wp; ncol = 128; c = r; }
        else         { src = Ws; ncol = 64;  c = r - 128; }
        f16 h[8];
        #pragma unroll
        for (int j = 0; j < 8; j++)
            h[j] = (f16)src[(size_t)(kg * 8 + j) * ncol + c];
        *(uint4*)&WT[(size_t)r * 1024 + kg * 8] = *(uint4*)h;
    } else {
        int g2 = gid - 24576;                 // < 8192
        int d = g2 >> 3, ng = g2 & 7;
        f16 h[8];
        #pragma unroll
        for (int j = 0; j < 8; j++)
            h[j] = (f16)Wo[(size_t)(ng * 8 + j) * D_ + d];
        *(uint4*)&WoT[(size_t)d * 64 + ng * 8] = *(uint4*)h;
    }
}

// ---------------------------------------------------------------------------
// Fused frontend v6: v4 structure (16 tok/block, 1024 blocks, 4 blocks/CU,
// conv-once-per-chunk) with the load schedule fixed: A-frag loads and the
// x prefetch LDX(c+1) are issued AFTER barrier (c), so no barrier drains an
// in-flight HBM/L2 load.  Barriers (b)/(c) drain only LDS (lgkm, cheap);
// barrier (a) drains a prefetch that had the whole MFMA phase to land.
// A-frags issued BEFORE LDX so the MFMA's vmcnt wait excludes the prefetch.
// ---------------------------------------------------------------------------
__global__ __launch_bounds__(256) void k_frontend(
    const float* __restrict__ x, const float* __restrict__ conv_w,
    const float* __restrict__ conv_b, const f16* __restrict__ WT,
    const float* __restrict__ bp, const float* __restrict__ bs,
    const float* __restrict__ dt_log,
    f16* __restrict__ zT, f16* __restrict__ cT)
{
    // layout: xh [20][72] f16 @0 (2880B); ch [16][72] f16 @2880 (2304B);
    // cwS [5][1024] f32 @5184 (20480B); total 25664B.
    // sE [3][16][68] f32 (13056B) aliases @0 in the epilogue.
    __shared__ __align__(16) char smem[25664];
    f16*   xh  = (f16*)smem;
    f16*   ch  = (f16*)(smem + 2880);
    float* cwS = (float*)(smem + 5184);
    float* sE  = (float*)smem;

    const int tid = threadIdx.x;
    const int w = tid >> 6, lane = tid & 63;
    const int r = lane & 15, q = lane >> 4;
    const int T0 = blockIdx.x * 16;
    const int bb = T0 >> 12;
    const int l0 = T0 & (L_ - 1);
    const int cw0 = w * 48;

    f32x4 acc[3] = {};
    float4 rA, rB;

    // stage conv weights + bias into LDS (once; visible after barrier (a))
    #pragma unroll
    for (int i = 0; i < 5; i++) {
        int idx = tid + 256 * i;
        float4 v = (idx < 1024) ? ((const float4*)conv_w)[idx]
                                : ((const float4*)conv_b)[idx - 1024];
        ((float4*)cwS)[idx] = v;
    }

    // staging: 20 rows x 16 float4 = 320 slots; tid<64 takes a second slot
    #define LDX(c0)                                                          \
        {                                                                    \
            {                                                                \
                int row = tid >> 4, g = tid & 15;                            \
                int l = l0 + row - 4;                                        \
                float4 v = make_float4(0.f, 0.f, 0.f, 0.f);                  \
                if (l >= 0)                                                  \
                    v = *(const float4*)&x[((size_t)(bb * L_ + l)) * D_      \
                                           + (c0) + g * 4];                  \
                rA = v;                                                      \
            }                                                                \
            if (tid < 64) {                                                  \
                int row = 16 + (tid >> 4), g = tid & 15;                     \
                int l = l0 + row - 4; /* >= 12, always valid */              \
                rB = *(const float4*)&x[((size_t)(bb * L_ + l)) * D_         \
                                        + (c0) + g * 4];                     \
            }                                                                \
        }

    LDX(0);
    for (int c = 0; c < 16; c++) {
        __syncthreads();   // (a) prev MFMA reads done; prefetch long landed
        {
            int row = tid >> 4, g = tid & 15;
            f16 h[4] = {(f16)rA.x, (f16)rA.y, (f16)rA.z, (f16)rA.w};
            *(uint2*)&xh[row * 72 + g * 4] = *(uint2*)h;
            if (tid < 64) {
                int row2 = 16 + (tid >> 4);
                f16 h2[4] = {(f16)rB.x, (f16)rB.y, (f16)rB.z, (f16)rB.w};
                *(uint2*)&xh[row2 * 72 + g * 4] = *(uint2*)h2;
            }
        }
        __syncthreads();   // (b) xh ready (drains lgkm only)

        const int k0 = c * 64;

        // conv: each thread computes 4 elems of the 16x64 chunk (once!)
        {
            const int row = tid >> 4;          // 0..15 (token t = l0+row)
            const int d4 = (tid & 15) * 4;
            const int dg = k0 + d4;
            f32x4 w0 = *(const f32x4*)&cwS[dg];
            f32x4 w1 = *(const f32x4*)&cwS[1024 + dg];
            f32x4 w2 = *(const f32x4*)&cwS[2048 + dg];
            f32x4 w3 = *(const f32x4*)&cwS[3072 + dg];
            f32x4 cb = *(const f32x4*)&cwS[4096 + dg];
            f16 x0[4], x1[4], x2[4], x3[4], ho[4];
            *(uint2*)x0 = *(const uint2*)&xh[(row + 1) * 72 + d4]; // t-3 (k=0)
            *(uint2*)x1 = *(const uint2*)&xh[(row + 2) * 72 + d4]; // t-2 (k=1)
            *(uint2*)x2 = *(const uint2*)&xh[(row + 3) * 72 + d4]; // t-1 (k=2)
            *(uint2*)x3 = *(const uint2*)&xh[(row + 4) * 72 + d4]; // t   (k=3)
            #pragma unroll
            for (int j = 0; j < 4; j++) {
                float s = cb[j];
                s = fmaf(w0[j], (float)x0[j], s);
                s = fmaf(w1[j], (float)x1[j], s);
                s = fmaf(w2[j], (float)x2[j], s);
                s = fmaf(w3[j], (float)x3[j], s);
                ho[j] = (f16)s;
            }
            *(uint2*)&ch[row * 72 + d4] = *(uint2*)ho;
        }
        __syncthreads();   // (c) ch ready (drains lgkm only)

        // A-frag loads issued NOW (consumed by MFMA via fine-grained vmcnt;
        // issued before LDX so waiting on af does not wait on the prefetch)
        half8 af[2][3];
        #pragma unroll
        for (int ks = 0; ks < 2; ks++)
            #pragma unroll
            for (int mf = 0; mf < 3; mf++)
                af[ks][mf] = *(const half8*)&WT[
                    (size_t)(cw0 + mf * 16 + r) * 1024 + k0 + ks * 32 + q * 8];

        // x prefetch for next chunk: in flight across the whole MFMA phase
        if (c < 15) LDX((c + 1) * 64);

        const bool needC = (cw0 < 128);          // w 0,1,2
        const bool needR = (cw0 + 32 >= 128);    // w 2,3
        #pragma unroll
        for (int ks = 0; ks < 2; ks++) {
            const int kl = ks * 32 + q * 8;
            half8 bc = {}, br = {};
            if (needC) bc = *(const half8*)&ch[r * 72 + kl];
            if (needR) br = *(const half8*)&xh[(r + 4) * 72 + kl];
            #pragma unroll
            for (int mf = 0; mf < 3; mf++) {
                const bool useConv = (cw0 + mf * 16) < 128;
                acc[mf] = __builtin_amdgcn_mfma_f32_16x16x32_f16(
                    af[ks][mf], useConv ? bc : br, acc[mf], 0, 0, 0);
            }
        }
    }

    // --- epilogue: bias + activation -> sE (aliases xh/ch/cwS) ---
    float* sB = sE;
    float* sC = sE + 16 * 68;
    float* sU = sE + 2 * 16 * 68;
    __syncthreads();   // all LDS reads of xh/ch done before overwrite
    #pragma unroll
    for (int mf = 0; mf < 3; mf++) {
        const int cb4 = cw0 + mf * 16 + q * 4;
        const int seg = cb4 >> 6;          // 0=Bt 1=Ct 2=u (frag-uniform)
        const int cl = cb4 & 63;
        const float4 bb4 = (seg == 2) ? *(const float4*)&bs[cl]
                                      : *(const float4*)&bp[cb4];
        float* dst = (seg == 0) ? sB : (seg == 1 ? sC : sU);
        float v0 = acc[mf][0] + bb4.x;
        float v1 = acc[mf][1] + bb4.y;
        float v2 = acc[mf][2] + bb4.z;
        float v3 = acc[mf][3] + bb4.w;
        if (seg == 0) {
            v0 = softplus_f(v0); v1 = softplus_f(v1);
            v2 = softplus_f(v2); v3 = softplus_f(v3);
        } else if (seg == 1) {
            v0 = tanh_f(v0); v1 = tanh_f(v1);
            v2 = tanh_f(v2); v3 = tanh_f(v3);
        }
        float4 vv = {v0, v1, v2, v3};
        *(float4*)&dst[r * 68 + cl] = vv;
    }
    __syncthreads();

    // --- fused combine: z = dt[n]*Bt*u, store zT/cT n-major ---
    {
        const int n = tid >> 2, tg = tid & 3;
        const float dtv = softplus_f(dt_log[n]);
        f16 hz[4], hc[4];
        #pragma unroll
        for (int j = 0; j < 4; j++) {
            const int t = tg * 4 + j;
            hz[j] = (f16)(dtv * sB[t * 68 + n] * sU[t * 68 + n]);
            hc[j] = (f16)sC[t * 68 + n];
        }
        size_t o = ((size_t)(bb * N_ + n)) * L_ + l0 + tg * 4;
        *(uint2*)&zT[o] = *(uint2*)hz;
        *(uint2*)&cT[o] = *(uint2*)hc;
    }
    #undef LDX
}

// ---------------------------------------------------------------------------
// Scan v2: 256 threads per (b,n) chain.  Thread t owns elems [16t,16t+16);
// serial 16-fma local reduce -> 64-lane shfl affine scan -> cross-wave
// stitch via LDS -> apply.  +i>>4 swizzle avoids 32-way bank conflicts.
// ---------------------------------------------------------------------------
#define ZI(i) ((i) + ((i) >> 4))
__global__ __launch_bounds__(256) void k_scan(
    const f16* __restrict__ zT, const f16* __restrict__ cT,
    const float* __restrict__ A_log, const float* __restrict__ dt_log,
    f16* __restrict__ yH)
{
    __shared__ float zs[4352];
    __shared__ float cs[4352];
    __shared__ float sA[4], sB[4];
    const int bn = blockIdx.x;
    const int n = bn & (N_ - 1);
    const int tid = threadIdx.x;
    const int lane = tid & 63, w = tid >> 6;
    const f16* zp = zT + (size_t)bn * L_;
    const f16* cp = cT + (size_t)bn * L_;

    #pragma unroll
    for (int it = 0; it < 2; it++) {
        int i = tid * 8 + it * 2048;
        uint4 rz = *(const uint4*)(zp + i);
        uint4 rc = *(const uint4*)(cp + i);
        const f16* hz = (const f16*)&rz;
        const f16* hc = (const f16*)&rc;
        #pragma unroll
        for (int k = 0; k < 8; k++) {
            zs[ZI(i + k)] = (float)hz[k];
            cs[ZI(i + k)] = (float)hc[k];
        }
    }
    __syncthreads();

    float dtv = softplus_f(dt_log[n]);
    float Av = -softplus_f(A_log[n]);
    float dec = fmaf(dtv, Av, 1.0f);

    const int base = tid * 17;           // ZI(tid*16)
    float s = 0.0f;
    #pragma unroll
    for (int j = 0; j < 16; j++) s = fmaf(dec, s, zs[base + j]);

    float d2 = dec * dec, d4 = d2 * d2, d8 = d4 * d4, d16 = d8 * d8;

    float Ag = d16, Bg = s;
    #pragma unroll
    for (int off = 1; off < 64; off <<= 1) {
        float Ap = __shfl_up(Ag, off);
        float Bp = __shfl_up(Bg, off);
        if (lane >= off) { Bg = fmaf(Ag, Bp, Bg); Ag *= Ap; }
    }
    if (lane == 63) { sA[w] = Ag; sB[w] = Bg; }
    __syncthreads();

    float Bc = 0.0f;                      // carry entering this wave
    for (int i = 0; i < w; i++) Bc = fmaf(sA[i], Bc, sB[i]);
    float Ae = __shfl_up(Ag, 1);          // exclusive within wave
    float Be = __shfl_up(Bg, 1);
    if (lane == 0) { Ae = 1.0f; Be = 0.0f; }
    float carry = fmaf(Ae, Bc, Be);       // state entering this thread

    float st = carry;
    #pragma unroll
    for (int j = 0; j < 16; j++) {
        st = fmaf(dec, st, zs[base + j]);
        zs[base + j] = cs[base + j] * st;
    }
    __syncthreads();

    f16* yp = yH + (size_t)bn * L_;
    #pragma unroll
    for (int it = 0; it < 2; it++) {
        int i = tid * 8 + it * 2048;
        f16 h[8];
        #pragma unroll
        for (int k = 0; k < 8; k++) h[k] = (f16)zs[ZI(i + k)];
        *(uint4*)&yp[i] = *(uint4*)h;
    }
}
#undef ZI

// ---------------------------------------------------------------------------
// Out GEMM: out[t][d] = y[t][:] @ Wo[:,d] + bo.  A = WoT (m=d), B = y (n=tok)
// -> D rows are d -> float4 coalesced stores.  Block 256 thr: 64 tok x 128 d,
// wave = 32 d x 64 tok.  Grid (256, 8) = 2048 blocks = 8/CU.
// ---------------------------------------------------------------------------
__global__ __launch_bounds__(256) void k_out(
    const f16* __restrict__ yH, const f16* __restrict__ WoT,
    const float* __restrict__ bo, float* __restrict__ out)
{
    __shared__ __align__(16) f16 ys[64 * 72];
    const int tid = threadIdx.x;
    const int w = tid >> 6, lane = tid & 63;
    const int r = lane & 15, q = lane >> 4;
    const int T0 = blockIdx.x * 64;
    const int bb = T0 >> 12, l0 = T0 & (L_ - 1);
    const int dw = blockIdx.y * 128 + w * 32;

    // stage y transpose: [n-major global] -> ys[t][n]
    {
        const int n = tid & 63, tg = tid >> 6;
        #pragma unroll
        for (int h2 = 0; h2 < 2; h2++) {
            uint4 v = *(const uint4*)&yH[((size_t)(bb * N_ + n)) * L_ + l0 + tg * 16 + h2 * 8];
            const f16* hh = (const f16*)&v;
            #pragma unroll
            for (int j = 0; j < 8; j++)
                ys[(tg * 16 + h2 * 8 + j) * 72 + n] = hh[j];
        }
    }
    __syncthreads();

    f32x4 acc[2][4] = {};
    #pragma unroll
    for (int ks = 0; ks < 2; ks++) {
        const int kk = ks * 32 + q * 8;
        half8 af[2];
        #pragma unroll
        for (int mf = 0; mf < 2; mf++)
            af[mf] = *(const half8*)&WoT[(size_t)(dw + mf * 16 + r) * 64 + kk];
        #pragma unroll
        for (int nf = 0; nf < 4; nf++) {
            half8 bf = *(const half8*)&ys[(nf * 16 + r) * 72 + kk];
            #pragma unroll
            for (int mf = 0; mf < 2; mf++)
                acc[mf][nf] = __builtin_amdgcn_mfma_f32_16x16x32_f16(
                    af[mf], bf, acc[mf][nf], 0, 0, 0);
        }
    }

    #pragma unroll
    for (int mf = 0; mf < 2; mf++) {
        const int d = dw + mf * 16 + q * 4;
        const float4 bb4 = *(const float4*)&bo[d];
        #pragma unroll
        for (int nf = 0; nf < 4; nf++) {
            const int t = T0 + nf * 16 + r;
            float4 o = {acc[mf][nf][0] + bb4.x, acc[mf][nf][1] + bb4.y,
                        acc[mf][nf][2] + bb4.z, acc[mf][nf][3] + bb4.w};
            *(float4*)&out[(size_t)t * D_ + d] = o;
        }
    }
}

// ---------------------------------------------------------------------------
extern "C" void kernel_launch(void* const* d_in, const int* in_sizes, int n_in,
                              void* d_out, int out_size, void* d_ws, size_t ws_size,
                              hipStream_t stream) {
    const float* x      = (const float*)d_in[0];
    const float* conv_w = (const float*)d_in[1];
    const float* conv_b = (const float*)d_in[2];
    const float* Wp     = (const float*)d_in[3];
    const float* bp     = (const float*)d_in[4];
    const float* Ws     = (const float*)d_in[5];
    const float* bs     = (const float*)d_in[6];
    const float* A_log  = (const float*)d_in[7];
    const float* dt_log = (const float*)d_in[8];
    const float* Wo     = (const float*)d_in[9];
    const float* bo     = (const float*)d_in[10];
    float* out = (float*)d_out;

    char* wsp = (char*)d_ws;
    f16* WT  = (f16*)wsp;                     // 384 KB
    f16* WoT = (f16*)(wsp + 393216);          // 128 KB
    f16* zT  = (f16*)(wsp + 524288);          // 2 MB [B,N,L]
    f16* cT  = (f16*)(wsp + 2621440);         // 2 MB
    f16* yH  = (f16*)(wsp + 4718592);         // 2 MB

    k_prepw<<<dim3(128), dim3(256), 0, stream>>>(Wp, Ws, Wo, WT, WoT);
    k_frontend<<<dim3(B_ * L_ / 16), dim3(256), 0, stream>>>(
        x, conv_w, conv_b, WT, bp, bs, dt_log, zT, cT);
    k_scan<<<dim3(B_ * N_), dim3(256), 0, stream>>>(zT, cT, A_log, dt_log, yH);
    k_out<<<dim3(B_ * L_ / 64, D_ / 128), dim3(256), 0, stream>>>(yH, WoT, bo, out);
}